// Round 5
// baseline (510.485 us; speedup 1.0000x reference)
//
#include <hip/hip_runtime.h>
#include <cmath>

#define NTOK 32768   // 8*4096 tokens
#define EMB  2048
#define NEXP 64
#define TOPK 8
#define BT   64      // tokens per block -> grid 512 = 2 blocks/CU
#define KC   64      // K per chunk (2 MFMA k-steps)
#define NCH  (EMB / KC)   // 32
#define TAU  1e-4f   // exact-recompute margin (~60 sigma of limb-GEMM error)

typedef __attribute__((ext_vector_type(8))) short bf16x8;   // 8 bf16 (4 VGPRs)
typedef __attribute__((ext_vector_type(4))) float f32x4;

union U4 { unsigned int u[4]; bf16x8 v; };

// W bf16 limb planes, 768 KB, laid out in gld_lds-linear order per chunk:
// g_wl[ch][ ((p*2+kk)*4+q)*512 + er*8 ]  (ushorts; p=plane, kk=32k-sub, q=8k-slot)
__device__ unsigned short g_wl[NCH][12288];

static __device__ __forceinline__ float uf(unsigned int x) { return __uint_as_float(x); }
static __device__ __forceinline__ unsigned int fu(float x) { return __float_as_uint(x); }

__device__ __forceinline__ void gld16(const void* g, void* lds) {
    __builtin_amdgcn_global_load_lds(
        (const __attribute__((address_space(1))) void*)g,
        (__attribute__((address_space(3))) void*)lds,
        16, 0, 0);
}

// ---- pre-kernel: split W into 3 truncated-bf16 limb planes (exact Sterbenz splits)
__global__ __launch_bounds__(512) void wsplit(const float* __restrict__ W) {
    const int ch  = blockIdx.x;
    const int tid = threadIdx.x;
    const int er = tid >> 3, kk = (tid >> 2) & 1, q = tid & 3;
    const int k0 = ch * KC + kk * 32 + q * 8;
    const float* src = &W[(size_t)er * EMB + k0];
    float x[8];
    #pragma unroll
    for (int j = 0; j < 8; ++j) x[j] = src[j];
    unsigned int P[3][4];
    #pragma unroll
    for (int m = 0; m < 4; ++m) {
        float x0 = x[2*m], x1 = x[2*m+1];
        unsigned int u0 = fu(x0), u1 = fu(x1);
        P[0][m] = (u0 >> 16) | (u1 & 0xffff0000u);
        float r0 = x0 - uf(u0 & 0xffff0000u), r1 = x1 - uf(u1 & 0xffff0000u);
        unsigned int w0 = fu(r0), w1 = fu(r1);
        P[1][m] = (w0 >> 16) | (w1 & 0xffff0000u);
        float s0 = r0 - uf(w0 & 0xffff0000u), s1 = r1 - uf(w1 & 0xffff0000u);
        P[2][m] = (fu(s0) >> 16) | (fu(s1) & 0xffff0000u);
    }
    #pragma unroll
    for (int p = 0; p < 3; ++p) {
        unsigned short* d = &g_wl[ch][((p*2 + kk)*4 + q)*512 + er*8];
        *(uint4*)(void*)d = make_uint4(P[p][0], P[p][1], P[p][2], P[p][3]);
    }
}

// LDS map (80 KB static):
//   xs[2][64][64] f32      @ 0      (2 x 16 KB)  X chunk; 16B-granule src-swizzled:
//                                   LDS[row][g] = X[row][(g&8)|((g&7)^(row&7))]
//   ws[2][12288] u16       @ 32768  (2 x 24 KB)  W limb planes, linear copy of g_wl[ch]
//   lg[64][66] f32         @ 0      (16896 B)    epilogue logits (after final barrier)
__global__ __launch_bounds__(512, 2) void router_mx(
    const float* __restrict__ X,   // [NTOK][EMB]
    const float* __restrict__ W,   // [NEXP][EMB]
    const float* __restrict__ Bv,  // [NEXP]
    float* __restrict__ out)       // probs [NTOK][64], then indices [NTOK][8] as f32
{
    __shared__ __align__(16) unsigned char smem[81920];
    float* xsBase          = (float*)smem;                       // + buf*4096 floats
    unsigned short* wsBase = (unsigned short*)(smem + 32768);    // + buf*12288 ushorts
    float* lg              = (float*)smem;                       // [64][66]

    const int tid  = threadIdx.x;
    const int lane = tid & 63;
    const int w    = tid >> 6;     // 0..7
    const int tg   = w >> 1;       // token group: rows tg*16 .. +15
    const int eh   = w & 1;        // expert half: cols eh*32 .. +31
    const int eL   = lane & 15;
    const int q    = lane >> 4;
    const int t0   = blockIdx.x * BT;

    f32x4 am[2], ac[2];            // per-cc head acc + correction acc
    #pragma unroll
    for (int t = 0; t < 2; ++t) {
        am[t] = (f32x4){0.f, 0.f, 0.f, 0.f};
        ac[t] = (f32x4){0.f, 0.f, 0.f, 0.f};
    }

    // ---- stage one chunk: exactly 5 gld_lds per wave (2 X + 3 W-limb)
    auto stage = [&](int ch, int buf) {
        float* xd = xsBase + buf * 4096;
        #pragma unroll
        for (int j = 0; j < 2; ++j) {
            const int rb  = (w * 2 + j) * 4;            // 4 rows per instr
            const int row = rb + (lane >> 4);
            const int gl  = (lane & 15) ^ (row & 7);    // swizzled source granule
            gld16(&X[(size_t)(t0 + row) * EMB + ch * KC + 4 * gl], xd + rb * 64);
        }
        unsigned short* wd = wsBase + buf * 12288;
        const unsigned short* wsrc = &g_wl[ch][0];
        #pragma unroll
        for (int j = 0; j < 3; ++j) {
            const int o = (w * 3 + j) * 512;            // 1 KB per instr, linear
            gld16(wsrc + o + lane * 8, wd + o);
        }
    };

    // ---- one K-chunk: 2 kk-steps x (12 ds_read-fed MFMAs + X limb split)
    auto compute = [&](int buf) {
        const float* xb          = xsBase + buf * 4096;
        const unsigned short* wb = wsBase + buf * 12288;
        const int row = tg * 16 + eL;
        #pragma unroll
        for (int kk = 0; kk < 2; ++kk) {
            bf16x8 Bf0[3], Bf1[3];
            #pragma unroll
            for (int p = 0; p < 3; ++p) {
                const int seg = ((p * 2 + kk) * 4 + q) * 512;
                Bf0[p] = *(const bf16x8*)(const void*)(wb + seg + (eh * 32 + eL) * 8);
                Bf1[p] = *(const bf16x8*)(const void*)(wb + seg + (eh * 32 + 16 + eL) * 8);
            }
            const int g0 = kk * 8 + ((2 * q) ^ (row & 7));
            const int g1 = kk * 8 + ((2 * q + 1) ^ (row & 7));
            const float4 aL = *(const float4*)&xb[row * 64 + 4 * g0];  // k = 8q..8q+3
            const float4 aH = *(const float4*)&xb[row * 64 + 4 * g1];  // k = 8q+4..8q+7
            U4 A1, A2, A3;
            const float e0[8] = {aL.x, aL.y, aL.z, aL.w, aH.x, aH.y, aH.z, aH.w};
            #pragma unroll
            for (int m = 0; m < 4; ++m) {
                float x0 = e0[2*m], x1 = e0[2*m+1];
                unsigned int u0 = fu(x0), u1 = fu(x1);
                A1.u[m] = (u0 >> 16) | (u1 & 0xffff0000u);
                float r0 = x0 - uf(u0 & 0xffff0000u), r1 = x1 - uf(u1 & 0xffff0000u);
                unsigned int w0 = fu(r0), w1 = fu(r1);
                A2.u[m] = (w0 >> 16) | (w1 & 0xffff0000u);
                float s0 = r0 - uf(w0 & 0xffff0000u), s1 = r1 - uf(w1 & 0xffff0000u);
                A3.u[m] = (fu(s0) >> 16) | (fu(s1) & 0xffff0000u);
            }
            am[0] = __builtin_amdgcn_mfma_f32_16x16x32_bf16(A1.v, Bf0[0], am[0], 0,0,0);
            ac[0] = __builtin_amdgcn_mfma_f32_16x16x32_bf16(A1.v, Bf0[1], ac[0], 0,0,0);
            ac[0] = __builtin_amdgcn_mfma_f32_16x16x32_bf16(A2.v, Bf0[0], ac[0], 0,0,0);
            ac[0] = __builtin_amdgcn_mfma_f32_16x16x32_bf16(A1.v, Bf0[2], ac[0], 0,0,0);
            ac[0] = __builtin_amdgcn_mfma_f32_16x16x32_bf16(A2.v, Bf0[1], ac[0], 0,0,0);
            ac[0] = __builtin_amdgcn_mfma_f32_16x16x32_bf16(A3.v, Bf0[0], ac[0], 0,0,0);
            am[1] = __builtin_amdgcn_mfma_f32_16x16x32_bf16(A1.v, Bf1[0], am[1], 0,0,0);
            ac[1] = __builtin_amdgcn_mfma_f32_16x16x32_bf16(A1.v, Bf1[1], ac[1], 0,0,0);
            ac[1] = __builtin_amdgcn_mfma_f32_16x16x32_bf16(A2.v, Bf1[0], ac[1], 0,0,0);
            ac[1] = __builtin_amdgcn_mfma_f32_16x16x32_bf16(A1.v, Bf1[2], ac[1], 0,0,0);
            ac[1] = __builtin_amdgcn_mfma_f32_16x16x32_bf16(A2.v, Bf1[1], ac[1], 0,0,0);
            ac[1] = __builtin_amdgcn_mfma_f32_16x16x32_bf16(A3.v, Bf1[0], ac[1], 0,0,0);
        }
    };

    // ---- main loop: counted-vmcnt gate, raw barriers, prefetch never drained
    stage(0, 0);
    for (int ch = 0; ch < NCH; ++ch) {
        const int cur = ch & 1;
        if (ch + 1 < NCH) {
            stage(ch + 1, cur ^ 1);                       // +5 loads in flight
            asm volatile("s_waitcnt vmcnt(5)" ::: "memory");  // chunk ch resident; ch+1 spans compute
        } else {
            asm volatile("s_waitcnt vmcnt(0)" ::: "memory");
        }
        __builtin_amdgcn_s_barrier();
        asm volatile("" ::: "memory");
        compute(cur);
        asm volatile("" ::: "memory");
        __builtin_amdgcn_s_barrier();   // all reads of buf done before next stage overwrites
    }

    // ---- logits -> LDS (f32, +bias). C layout: col = lane&15, row = (lane>>4)*4 + reg.
    float* probs = out;
    float* idxo  = out + (size_t)NTOK * NEXP;
    const float bb0 = Bv[eh * 32 + eL];
    const float bb1 = Bv[eh * 32 + 16 + eL];
    #pragma unroll
    for (int cc = 0; cc < 2; ++cc) {
        const int e = eh * 32 + cc * 16 + eL;
        const float bbv = cc ? bb1 : bb0;
        #pragma unroll
        for (int i = 0; i < 4; ++i) {
            const int r = tg * 16 + q * 4 + i;
            lg[r * 66 + e] = (am[cc][i] + ac[cc][i]) + bbv;
        }
    }
    __syncthreads();

    // ---- whole-wave exact f64 redo for margin-critical tokens (latency-pipelined)
    auto slowToken = [&](int Tg) {
        const float* xr = X + (size_t)Tg * EMB;
        const float* wr = W + (size_t)lane * EMB;
        double s0 = 0.0, s1 = 0.0, s2 = 0.0, s3 = 0.0;
        for (int k = 0; k < EMB; k += 16) {
            const float4 xa = *(const float4*)&xr[k];
            const float4 xb = *(const float4*)&xr[k + 4];
            const float4 xc = *(const float4*)&xr[k + 8];
            const float4 xd = *(const float4*)&xr[k + 12];
            const float4 wa = *(const float4*)&wr[k];
            const float4 wb = *(const float4*)&wr[k + 4];
            const float4 wc = *(const float4*)&wr[k + 8];
            const float4 wd = *(const float4*)&wr[k + 12];
            s0 += (double)xa.x * wa.x + (double)xa.y * wa.y
                + (double)xa.z * wa.z + (double)xa.w * wa.w;
            s1 += (double)xb.x * wb.x + (double)xb.y * wb.y
                + (double)xb.z * wb.z + (double)xb.w * wb.w;
            s2 += (double)xc.x * wc.x + (double)xc.y * wc.y
                + (double)xc.z * wc.z + (double)xc.w * wc.w;
            s3 += (double)xd.x * wd.x + (double)xd.y * wd.y
                + (double)xd.z * wd.z + (double)xd.w * wd.w;
        }
        double ex = (double)Bv[lane] + ((s0 + s1) + (s2 + s3));
        bool selb = false; int myrank = 0;
        double m0d = 0.0; float ss = 0.f;
        #pragma unroll
        for (int it = 0; it < TOPK; ++it) {
            double bv = selb ? -1.0e300 : ex; int be = lane;
            #pragma unroll
            for (int off = 1; off <= 32; off <<= 1) {
                const double ov = __shfl_xor(bv, off, 64);
                const int    oe = __shfl_xor(be, off, 64);
                if (ov > bv || (ov == bv && oe < be)) { bv = ov; be = oe; }
            }
            if (it == 0) m0d = bv;
            ss += __expf((float)(bv - m0d));
            if (lane == be) { selb = true; myrank = it; }
        }
        probs[(size_t)Tg * NEXP + lane] = selb ? __expf((float)(ex - m0d)) / ss : 0.f;
        if (selb) idxo[(size_t)Tg * TOPK + myrank] = (float)lane;
    };

    // ---- fast top-8 + masked softmax; wave w owns local tokens w*8 .. +7
    #pragma unroll
    for (int i = 0; i < 2; ++i) {
        const int T = w * 8 + i * 4 + q;        // local token (one per 16-lane group)
        float v[4];
        #pragma unroll
        for (int c = 0; c < 4; ++c) v[c] = lg[T * 66 + c * 16 + eL];

        unsigned sel = 0;
        float m0 = 0.f, ssum = 0.f, prev = 0.f, mingap = 1e30f;
        int myIdx = 0;
        #pragma unroll
        for (int it = 0; it <= TOPK; ++it) {    // 9 ranks: need gap to rank-8
            float bv = -1e30f; int be = 1 << 30;
            #pragma unroll
            for (int c = 0; c < 4; ++c)
                if (!((sel >> c) & 1) && v[c] > bv) { bv = v[c]; be = c * 16 + eL; }
            float gv = bv; int ge = be;
            #pragma unroll
            for (int off = 1; off <= 8; off <<= 1) {
                const float ov = __shfl_xor(gv, off, 64);
                const int   oe = __shfl_xor(ge, off, 64);
                if (ov > gv || (ov == gv && oe < ge)) { gv = ov; ge = oe; }
            }
            if (it == 0) m0 = gv;
            else mingap = fminf(mingap, prev - gv);
            prev = gv;
            if (it < TOPK) {
                ssum += __expf(gv - m0);
                if ((ge & 15) == eL) sel |= 1u << (ge >> 4);
                if (eL == it) myIdx = ge;
            }
        }
        const int Tg = t0 + T;
        const float inv = 1.0f / ssum;
        #pragma unroll
        for (int c = 0; c < 4; ++c) {
            const float p = ((sel >> c) & 1) ? __expf(v[c] - m0) * inv : 0.0f;
            probs[(size_t)Tg * NEXP + c * 16 + eL] = p;
        }
        if (eL < TOPK) idxo[(size_t)Tg * TOPK + eL] = (float)myIdx;

        // margin guard: any adjacent gap among ranks 0..8 below TAU -> exact redo
        const unsigned long long fb = __ballot(mingap < TAU);
        for (int q2 = 0; q2 < 4; ++q2)
            if ((fb >> (q2 * 16)) & 1) slowToken(t0 + w * 8 + i * 4 + q2);
    }
}

extern "C" void kernel_launch(void* const* d_in, const int* in_sizes, int n_in,
                              void* d_out, int out_size, void* d_ws, size_t ws_size,
                              hipStream_t stream) {
    const float* X = (const float*)d_in[0];
    const float* W = (const float*)d_in[1];
    const float* B = (const float*)d_in[2];
    wsplit<<<NCH, 512, 0, stream>>>(W);
    router_mx<<<NTOK / BT, 512, 0, stream>>>(X, W, B, (float*)d_out);
}

// Round 8
// 497.990 us; speedup vs baseline: 1.0251x; 1.0251x over previous
//
#include <hip/hip_runtime.h>
#include <cmath>

#define NTOK 32768   // 8*4096 tokens
#define EMB  2048
#define NEXP 64
#define TOPK 8
#define BT   64      // tokens per block -> grid 512
#define KC   64      // K per chunk (2 MFMA k-steps)
#define NCH  (EMB / KC)   // 32
#define TAU  1e-4f   // exact-recompute margin (~60 sigma of limb-GEMM error)

typedef __attribute__((ext_vector_type(8))) short bf16x8;   // 8 bf16 (4 VGPRs)
typedef __attribute__((ext_vector_type(4))) float f32x4;

union U4 { unsigned int u[4]; bf16x8 v; };

// W bf16 limb planes, 768 KB, laid out in gld_lds-linear order per chunk:
// g_wl[ch][ ((p*2+kk)*4+q)*512 + er*8 ]  (ushorts; p=plane, kk=32k-sub, q=8k-slot)
__device__ unsigned short g_wl[NCH][12288];
// W^T for the exact-redo path, lane-coalesced: g_wt4[(k>>2)*256 + e*4 + (k&3)] = W[e][k]
__device__ float g_wt4[EMB * 64];

static __device__ __forceinline__ float uf(unsigned int x) { return __uint_as_float(x); }
static __device__ __forceinline__ unsigned int fu(float x) { return __float_as_uint(x); }

__device__ __forceinline__ void gld16(const void* g, void* lds) {
    __builtin_amdgcn_global_load_lds(
        (const __attribute__((address_space(1))) void*)g,
        (__attribute__((address_space(3))) void*)lds,
        16, 0, 0);
}

// ---- pre-kernel: split W into 3 truncated-bf16 limb planes (exact Sterbenz splits)
//      + write coalesced W^T copy for the slow path
__global__ __launch_bounds__(512) void wsplit(const float* __restrict__ W) {
    const int ch  = blockIdx.x;
    const int tid = threadIdx.x;
    const int er = tid >> 3, kk = (tid >> 2) & 1, q = tid & 3;
    const int k0 = ch * KC + kk * 32 + q * 8;
    const float* src = &W[(size_t)er * EMB + k0];
    float x[8];
    #pragma unroll
    for (int j = 0; j < 8; ++j) x[j] = src[j];
    #pragma unroll
    for (int j = 0; j < 8; ++j) {
        const int k = k0 + j;
        g_wt4[(k >> 2) * 256 + er * 4 + (k & 3)] = x[j];
    }
    unsigned int P[3][4];
    #pragma unroll
    for (int m = 0; m < 4; ++m) {
        float x0 = x[2*m], x1 = x[2*m+1];
        unsigned int u0 = fu(x0), u1 = fu(x1);
        P[0][m] = (u0 >> 16) | (u1 & 0xffff0000u);
        float r0 = x0 - uf(u0 & 0xffff0000u), r1 = x1 - uf(u1 & 0xffff0000u);
        unsigned int w0 = fu(r0), w1 = fu(r1);
        P[1][m] = (w0 >> 16) | (w1 & 0xffff0000u);
        float s0 = r0 - uf(w0 & 0xffff0000u), s1 = r1 - uf(w1 & 0xffff0000u);
        P[2][m] = (fu(s0) >> 16) | (fu(s1) & 0xffff0000u);
    }
    #pragma unroll
    for (int p = 0; p < 3; ++p) {
        unsigned short* d = &g_wl[ch][((p*2 + kk)*4 + q)*512 + er*8];
        *(uint4*)(void*)d = make_uint4(P[p][0], P[p][1], P[p][2], P[p][3]);
    }
}

// LDS map (80 KB static):
//   xs[2][64][64] f32      @ 0      (2 x 16 KB)  X chunk; 16B-granule src-swizzled:
//                                   LDS[row][g] = X[row][(g&8)|((g&7)^(row&7))]
//   ws[2][12288] u16       @ 32768  (2 x 24 KB)  W limb planes, linear copy of g_wl[ch]
//   lg[64][66] f32         @ 0      (16896 B)    epilogue logits (after final barrier)
__global__ __launch_bounds__(512, 2) void router_mx(
    const float* __restrict__ X,   // [NTOK][EMB]
    const float* __restrict__ W,   // [NEXP][EMB]
    const float* __restrict__ Bv,  // [NEXP]
    float* __restrict__ out)       // probs [NTOK][64], then indices [NTOK][8] as f32
{
    __shared__ __align__(16) unsigned char smem[81920];
    float* xsBase          = (float*)smem;                       // + buf*4096 floats
    unsigned short* wsBase = (unsigned short*)(smem + 32768);    // + buf*12288 ushorts
    float* lg              = (float*)smem;                       // [64][66]

    const int tid  = threadIdx.x;
    const int lane = tid & 63;
    const int w    = tid >> 6;     // 0..7
    const int tg   = w >> 1;       // token group: rows tg*16 .. +15
    const int eh   = w & 1;        // expert half: cols eh*32 .. +31
    const int eL   = lane & 15;
    const int q    = lane >> 4;
    const int t0   = blockIdx.x * BT;

    f32x4 am[2], ac[2];            // per-cc head acc + correction acc
    #pragma unroll
    for (int t = 0; t < 2; ++t) {
        am[t] = (f32x4){0.f, 0.f, 0.f, 0.f};
        ac[t] = (f32x4){0.f, 0.f, 0.f, 0.f};
    }

    // ---- stage one chunk: exactly 5 gld_lds per wave (2 X + 3 W-limb)
    auto stage = [&](int ch, int buf) {
        float* xd = xsBase + buf * 4096;
        #pragma unroll
        for (int j = 0; j < 2; ++j) {
            const int rb  = (w * 2 + j) * 4;            // 4 rows per instr
            const int row = rb + (lane >> 4);
            const int gl  = (lane & 15) ^ (row & 7);    // swizzled source granule
            gld16(&X[(size_t)(t0 + row) * EMB + ch * KC + 4 * gl], xd + rb * 64);
        }
        unsigned short* wd = wsBase + buf * 12288;
        const unsigned short* wsrc = &g_wl[ch][0];
        #pragma unroll
        for (int j = 0; j < 3; ++j) {
            const int o = (w * 3 + j) * 512;            // 1 KB per instr, linear
            gld16(wsrc + o + lane * 8, wd + o);
        }
    };

    // ---- one K-chunk: 2 kk-steps x (12 ds_read-fed MFMAs + X limb split)
    auto compute = [&](int buf) {
        const float* xb          = xsBase + buf * 4096;
        const unsigned short* wb = wsBase + buf * 12288;
        const int row = tg * 16 + eL;
        #pragma unroll
        for (int kk = 0; kk < 2; ++kk) {
            bf16x8 Bf0[3], Bf1[3];
            #pragma unroll
            for (int p = 0; p < 3; ++p) {
                const int seg = ((p * 2 + kk) * 4 + q) * 512;
                Bf0[p] = *(const bf16x8*)(const void*)(wb + seg + (eh * 32 + eL) * 8);
                Bf1[p] = *(const bf16x8*)(const void*)(wb + seg + (eh * 32 + 16 + eL) * 8);
            }
            const int g0 = kk * 8 + ((2 * q) ^ (row & 7));
            const int g1 = kk * 8 + ((2 * q + 1) ^ (row & 7));
            const float4 aL = *(const float4*)&xb[row * 64 + 4 * g0];  // k = 8q..8q+3
            const float4 aH = *(const float4*)&xb[row * 64 + 4 * g1];  // k = 8q+4..8q+7
            U4 A1, A2, A3;
            const float e0[8] = {aL.x, aL.y, aL.z, aL.w, aH.x, aH.y, aH.z, aH.w};
            #pragma unroll
            for (int m = 0; m < 4; ++m) {
                float x0 = e0[2*m], x1 = e0[2*m+1];
                unsigned int u0 = fu(x0), u1 = fu(x1);
                A1.u[m] = (u0 >> 16) | (u1 & 0xffff0000u);
                float r0 = x0 - uf(u0 & 0xffff0000u), r1 = x1 - uf(u1 & 0xffff0000u);
                unsigned int w0 = fu(r0), w1 = fu(r1);
                A2.u[m] = (w0 >> 16) | (w1 & 0xffff0000u);
                float s0 = r0 - uf(w0 & 0xffff0000u), s1 = r1 - uf(w1 & 0xffff0000u);
                A3.u[m] = (fu(s0) >> 16) | (fu(s1) & 0xffff0000u);
            }
            am[0] = __builtin_amdgcn_mfma_f32_16x16x32_bf16(A1.v, Bf0[0], am[0], 0,0,0);
            ac[0] = __builtin_amdgcn_mfma_f32_16x16x32_bf16(A1.v, Bf0[1], ac[0], 0,0,0);
            ac[0] = __builtin_amdgcn_mfma_f32_16x16x32_bf16(A2.v, Bf0[0], ac[0], 0,0,0);
            ac[0] = __builtin_amdgcn_mfma_f32_16x16x32_bf16(A1.v, Bf0[2], ac[0], 0,0,0);
            ac[0] = __builtin_amdgcn_mfma_f32_16x16x32_bf16(A2.v, Bf0[1], ac[0], 0,0,0);
            ac[0] = __builtin_amdgcn_mfma_f32_16x16x32_bf16(A3.v, Bf0[0], ac[0], 0,0,0);
            am[1] = __builtin_amdgcn_mfma_f32_16x16x32_bf16(A1.v, Bf1[0], am[1], 0,0,0);
            ac[1] = __builtin_amdgcn_mfma_f32_16x16x32_bf16(A1.v, Bf1[1], ac[1], 0,0,0);
            ac[1] = __builtin_amdgcn_mfma_f32_16x16x32_bf16(A2.v, Bf1[0], ac[1], 0,0,0);
            ac[1] = __builtin_amdgcn_mfma_f32_16x16x32_bf16(A1.v, Bf1[2], ac[1], 0,0,0);
            ac[1] = __builtin_amdgcn_mfma_f32_16x16x32_bf16(A2.v, Bf1[1], ac[1], 0,0,0);
            ac[1] = __builtin_amdgcn_mfma_f32_16x16x32_bf16(A3.v, Bf1[0], ac[1], 0,0,0);
        }
    };

    // ---- main loop: counted-vmcnt gate, raw barriers, prefetch never drained
    stage(0, 0);
    for (int ch = 0; ch < NCH; ++ch) {
        const int cur = ch & 1;
        if (ch + 1 < NCH) {
            stage(ch + 1, cur ^ 1);                       // +5 loads in flight
            asm volatile("s_waitcnt vmcnt(5)" ::: "memory");  // chunk ch resident; ch+1 spans compute
        } else {
            asm volatile("s_waitcnt vmcnt(0)" ::: "memory");
        }
        __builtin_amdgcn_s_barrier();
        asm volatile("" ::: "memory");
        compute(cur);
        asm volatile("" ::: "memory");
        __builtin_amdgcn_s_barrier();   // all reads of buf done before next stage overwrites
    }

    // ---- logits -> LDS (f32, +bias). C layout: col = lane&15, row = (lane>>4)*4 + reg.
    float* probs = out;
    float* idxo  = out + (size_t)NTOK * NEXP;
    const float bb0 = Bv[eh * 32 + eL];
    const float bb1 = Bv[eh * 32 + 16 + eL];
    #pragma unroll
    for (int cc = 0; cc < 2; ++cc) {
        const int e = eh * 32 + cc * 16 + eL;
        const float bbv = cc ? bb1 : bb0;
        #pragma unroll
        for (int i = 0; i < 4; ++i) {
            const int r = tg * 16 + q * 4 + i;
            lg[r * 66 + e] = (am[cc][i] + ac[cc][i]) + bbv;
        }
    }
    __syncthreads();

    // ---- whole-wave exact f64 redo for margin-critical tokens.
    // COALESCED: lane e reads W^T[k][e] (g_wt4 layout) -> 1KB/instr, no 64-way scatter.
    auto slowToken = [&](int Tg) {
        const float* xr = X + (size_t)Tg * EMB;
        double s0 = 0.0, s1 = 0.0, s2 = 0.0, s3 = 0.0;
        for (int k = 0; k < EMB; k += 8) {
            const float4 xa = *(const float4*)&xr[k];       // uniform -> broadcast
            const float4 xb = *(const float4*)&xr[k + 4];
            const float4 wa = *(const float4*)&g_wt4[(k >> 2) * 256 + lane * 4];
            const float4 wb = *(const float4*)&g_wt4[((k >> 2) + 1) * 256 + lane * 4];
            s0 += (double)xa.x * wa.x + (double)xb.x * wb.x;
            s1 += (double)xa.y * wa.y + (double)xb.y * wb.y;
            s2 += (double)xa.z * wa.z + (double)xb.z * wb.z;
            s3 += (double)xa.w * wa.w + (double)xb.w * wb.w;
        }
        double ex = (double)Bv[lane] + ((s0 + s1) + (s2 + s3));
        bool selb = false; int myrank = 0;
        double m0d = 0.0; float ss = 0.f;
        #pragma unroll
        for (int it = 0; it < TOPK; ++it) {
            double bv = selb ? -1.0e300 : ex; int be = lane;
            #pragma unroll
            for (int off = 1; off <= 32; off <<= 1) {
                const double ov = __shfl_xor(bv, off, 64);
                const int    oe = __shfl_xor(be, off, 64);
                if (ov > bv || (ov == bv && oe < be)) { bv = ov; be = oe; }
            }
            if (it == 0) m0d = bv;
            ss += __expf((float)(bv - m0d));
            if (lane == be) { selb = true; myrank = it; }
        }
        probs[(size_t)Tg * NEXP + lane] = selb ? __expf((float)(ex - m0d)) / ss : 0.f;
        if (selb) idxo[(size_t)Tg * TOPK + myrank] = (float)lane;
    };

    // ---- fast top-8 + masked softmax; wave w owns local tokens w*8 .. +7
    #pragma unroll
    for (int i = 0; i < 2; ++i) {
        const int T = w * 8 + i * 4 + q;        // local token (one per 16-lane group)
        float v[4];
        #pragma unroll
        for (int c = 0; c < 4; ++c) v[c] = lg[T * 66 + c * 16 + eL];

        unsigned sel = 0;
        float m0 = 0.f, ssum = 0.f, prev = 0.f, mingap = 1e30f;
        int myIdx = 0;
        #pragma unroll
        for (int it = 0; it <= TOPK; ++it) {    // 9 ranks: need gap to rank-8
            float bv = -1e30f; int be = 1 << 30;
            #pragma unroll
            for (int c = 0; c < 4; ++c)
                if (!((sel >> c) & 1) && v[c] > bv) { bv = v[c]; be = c * 16 + eL; }
            float gv = bv; int ge = be;
            #pragma unroll
            for (int off = 1; off <= 8; off <<= 1) {
                const float ov = __shfl_xor(gv, off, 64);
                const int   oe = __shfl_xor(ge, off, 64);
                if (ov > gv || (ov == gv && oe < ge)) { gv = ov; ge = oe; }
            }
            if (it == 0) m0 = gv;
            else mingap = fminf(mingap, prev - gv);
            prev = gv;
            if (it < TOPK) {
                ssum += __expf(gv - m0);
                if ((ge & 15) == eL) sel |= 1u << (ge >> 4);
                if (eL == it) myIdx = ge;
            }
        }
        const int Tg = t0 + T;
        const float inv = 1.0f / ssum;
        #pragma unroll
        for (int c = 0; c < 4; ++c) {
            const float p = ((sel >> c) & 1) ? __expf(v[c] - m0) * inv : 0.0f;
            probs[(size_t)Tg * NEXP + c * 16 + eL] = p;
        }
        if (eL < TOPK) idxo[(size_t)Tg * TOPK + eL] = (float)myIdx;

        // margin guard: any adjacent gap among ranks 0..8 below TAU -> exact redo
        const unsigned long long fb = __ballot(mingap < TAU);
        for (int q2 = 0; q2 < 4; ++q2)
            if ((fb >> (q2 * 16)) & 1) slowToken(t0 + w * 8 + i * 4 + q2);
    }
}

extern "C" void kernel_launch(void* const* d_in, const int* in_sizes, int n_in,
                              void* d_out, int out_size, void* d_ws, size_t ws_size,
                              hipStream_t stream) {
    const float* X = (const float*)d_in[0];
    const float* W = (const float*)d_in[1];
    const float* B = (const float*)d_in[2];
    wsplit<<<NCH, 512, 0, stream>>>(W);
    router_mx<<<NTOK / BT, 512, 0, stream>>>(X, W, B, (float*)d_out);
}